// Round 3
// baseline (1966.875 us; speedup 1.0000x reference)
//
#include <hip/hip_runtime.h>
#include <hip/hip_bf16.h>

// Problem constants
#define BB 16
#define NN 8192
#define SS 1024
#define GG 32
// sortable(1.0f) = 0x3F800000 ^ 0x80000000
#define SORT_R2 0xBF800000u

typedef float v2f __attribute__((ext_vector_type(2)));

__device__ __forceinline__ unsigned sortable(float f) {
    unsigned u = __float_as_uint(f);
    return u ^ ((unsigned)(((int)u) >> 31) | 0x80000000u);
}

__device__ __forceinline__ float fmax3(float a, float b, float c) {
    return fmaxf(fmaxf(a, b), c);   // fuses to v_max3_f32
}

// ---------------------------------------------------------------------------
// Kernel 1: pack pts4[b][n] = {x, y, z, (x*x+y*y)+z*z}  (rn ops, no contraction)
// ---------------------------------------------------------------------------
__global__ __launch_bounds__(256) void k_pts(const float* __restrict__ coor,
                                             float4* __restrict__ pts4) {
    int i = blockIdx.x * 256 + threadIdx.x;   // 0 .. B*N-1
    int b = i >> 13, n = i & (NN - 1);
    const float* cb = coor + (long)b * 3 * NN;
    float x = cb[n], y = cb[NN + n], z = cb[2 * NN + n];
    float pn = __fadd_rn(__fadd_rn(__fmul_rn(x, x), __fmul_rn(y, y)), __fmul_rn(z, z));
    pts4[i] = make_float4(x, y, z, pn);
}

// ---------------------------------------------------------------------------
// Kernel 2: transpose fea (B,64,N) -> feaT (B,N,64)
// ---------------------------------------------------------------------------
__global__ __launch_bounds__(256) void k_tr(const float* __restrict__ fea,
                                            float* __restrict__ feaT) {
    __shared__ float tile[64][65];
    int b = blockIdx.y, n0 = blockIdx.x * 64;
    int t = threadIdx.x;
    int nl = t & 63, cb = t >> 6;
#pragma unroll
    for (int i = 0; i < 16; i++) {
        int c = cb * 16 + i;
        tile[nl][c] = fea[((long)b * 64 + c) * NN + n0 + nl];
    }
    __syncthreads();
    int cl = t & 63, nb = t >> 6;
#pragma unroll
    for (int i = 0; i < 16; i++) {
        int n = nb * 16 + i;
        feaT[((long)b * NN + n0 + n) * 64 + cl] = tile[n][cl];
    }
}

// ---------------------------------------------------------------------------
// Kernel 3: farthest point sampling. One block (512 thr) per batch.
// v3: packed-fp32 distance math (v_pk_add/mul via float2 vectors, contract
// OFF so every op stays a discrete rn mul/add — bit-exact vs reference);
// value-first reduction: f32 max butterfly + equality scan + u32 min-index
// butterfly replaces the u64 argmax machinery. Exact first-index ties.
// ---------------------------------------------------------------------------
__global__ __launch_bounds__(512) void k_fps(const float4* __restrict__ pts4,
                                             float4* __restrict__ qpts,
                                             float* __restrict__ out) {
#pragma clang fp contract(off)
    __shared__ float xs[NN], ys[NN], zs[NN];
    __shared__ int scur[SS];
    __shared__ __align__(16) float redv[8];
    __shared__ __align__(16) unsigned redi[8];
    int b = blockIdx.x;
    int t = threadIdx.x;
    const float4* P = pts4 + (long)b * NN;

    // pair j, half h -> point p = t + (2j+h)*512
    v2f px[8], py[8], pz[8], dist[8];
#pragma unroll
    for (int j = 0; j < 8; j++) {
        int p0 = t + (2 * j) * 512;
        int p1 = t + (2 * j + 1) * 512;
        float4 a = P[p0];
        float4 c = P[p1];
        px[j] = v2f{a.x, c.x};
        py[j] = v2f{a.y, c.y};
        pz[j] = v2f{a.z, c.z};
        dist[j] = v2f{1e10f, 1e10f};
        xs[p0] = a.x; ys[p0] = a.y; zs[p0] = a.z;
        xs[p1] = c.x; ys[p1] = c.y; zs[p1] = c.z;
    }
    __syncthreads();

    int cur = 0;
    for (int s = 0; s < SS; s++) {
        float cx = xs[cur], cy = ys[cur], cz = zs[cur];
        if (t == 0) scur[s] = cur;
        v2f cx2 = v2f{cx, cx}, cy2 = v2f{cy, cy}, cz2 = v2f{cz, cz};
#pragma unroll
        for (int j = 0; j < 8; j++) {
            v2f dx = px[j] - cx2;
            v2f dy = py[j] - cy2;
            v2f dz = pz[j] - cz2;
            v2f xx = dx * dx;
            v2f yy = dy * dy;
            v2f zz = dz * dz;
            v2f sm = xx + yy;
            v2f d = sm + zz;
            dist[j].x = fminf(dist[j].x, d.x);
            dist[j].y = fminf(dist[j].y, d.y);
        }
        // per-thread max (value only), max3 tree over 16 scalars
        float t0 = fmax3(dist[0].x, dist[0].y, dist[1].x);
        float t1 = fmax3(dist[1].y, dist[2].x, dist[2].y);
        float t2 = fmax3(dist[3].x, dist[3].y, dist[4].x);
        float t3 = fmax3(dist[4].y, dist[5].x, dist[5].y);
        float t4 = fmax3(dist[6].x, dist[6].y, dist[7].x);
        float bv = fmaxf(fmax3(t0, t1, t2), fmax3(t3, t4, dist[7].y));
        // wave butterfly max (f32)
#pragma unroll
        for (int m = 1; m < 64; m <<= 1) bv = fmaxf(bv, __shfl_xor(bv, m, 64));
        if ((t & 63) == 0) redv[t >> 6] = bv;
        __syncthreads();
        float4 r0 = *(const float4*)redv;
        float4 r1 = *(const float4*)(redv + 4);
        float gmax = fmaxf(fmax3(r0.x, r0.y, r0.z),
                           fmax3(r0.w, fmax3(r1.x, r1.y, r1.z), r1.w));
        // earliest local index holding gmax (descending scan => smallest wins)
        int jj = 255;
#pragma unroll
        for (int j = 7; j >= 0; j--) {
            jj = (dist[j].y == gmax) ? (2 * j + 1) : jj;
            jj = (dist[j].x == gmax) ? (2 * j) : jj;
        }
        unsigned lp = (unsigned)(t + jj * 512);   // no match -> >= 130560 sentinel
#pragma unroll
        for (int m = 1; m < 64; m <<= 1) {
            unsigned o = __shfl_xor(lp, m, 64);
            lp = (o < lp) ? o : lp;
        }
        if ((t & 63) == 0) redi[t >> 6] = lp;
        __syncthreads();
        uint4 i0 = *(const uint4*)redi;
        uint4 i1 = *(const uint4*)(redi + 4);
        unsigned c0 = min(min(i0.x, i0.y), min(i0.z, i0.w));
        unsigned c1 = min(min(i1.x, i1.y), min(i1.z, i1.w));
        cur = (int)min(c0, c1);
    }
    __syncthreads();

    // epilogue: write new_coor (B,3,S) and query points from recorded indices
#pragma unroll
    for (int s = t; s < SS; s += 512) {
        int c = scur[s];
        float cx = xs[c], cy = ys[c], cz = zs[c];
        out[(long)b * 3 * SS + s]          = cx;
        out[(long)b * 3 * SS + SS + s]     = cy;
        out[(long)b * 3 * SS + 2 * SS + s] = cz;
        float qn = __fadd_rn(__fadd_rn(__fmul_rn(cx, cx), __fmul_rn(cy, cy)),
                             __fmul_rn(cz, cz));
        qpts[(long)b * SS + s] = make_float4(cx, cy, cz, qn);
    }
}

// ---------------------------------------------------------------------------
// Kernel 4: exact 32-NN per query (one wave per query), reference formula
// d = (qn - 2*dot) + pn; stable tie-break by index (matches lax.top_k);
// radius filter d > 1.0 -> replace with nearest index.
// ---------------------------------------------------------------------------
#define SKEW(p) ((p) + ((p) >> 5))
__global__ __launch_bounds__(64) void k_knn(const float4* __restrict__ pts4,
                                            const float4* __restrict__ qpts,
                                            int* __restrict__ gidx) {
    __shared__ unsigned dk[NN + NN / 32];   // 8448
    int Q = blockIdx.x;                      // b*1024 + s
    int b = Q >> 10;
    int l = threadIdx.x;
    float4 q = qpts[Q];
    const float4* P = pts4 + (long)b * NN;

    unsigned bmin = 0xFFFFFFFFu;
    int bpos = 0;
    for (int j = 0; j < 128; j++) {
        int p = j * 64 + l;
        float4 v = P[p];
        float dot = __fadd_rn(__fadd_rn(__fmul_rn(q.x, v.x), __fmul_rn(q.y, v.y)),
                              __fmul_rn(q.z, v.z));
        float d = __fadd_rn(__fsub_rn(q.w, __fmul_rn(2.0f, dot)), v.w);
        unsigned u = sortable(d);
        dk[SKEW(p)] = u;
        if (u < bmin) { bmin = u; bpos = p; }   // ascending p -> earliest index on tie
    }
    __syncthreads();

    int pos0 = 0;
    for (int k = 0; k < GG; k++) {
        unsigned long long key = ((unsigned long long)bmin << 32) | (unsigned)bpos;
#pragma unroll
        for (int m = 1; m < 64; m <<= 1) {
            unsigned long long o = __shfl_xor(key, m, 64);
            key = (o < key) ? o : key;
        }
        int kpos = (int)(key & 0xFFFFFFFFu);
        unsigned kval = (unsigned)(key >> 32);
        if (k == 0) pos0 = kpos;
        if (l == 0) gidx[(long)Q * GG + k] = (kval > SORT_R2) ? pos0 : kpos;
        int owner = kpos & 63;
        if (l == owner) dk[SKEW(kpos)] = 0xFFFFFFFFu;   // invalidate popped slot
        __syncthreads();
        // cooperative rescan of owner's column (its 128 points)
        int p1 = l * 64 + owner;
        int p2 = (l + 64) * 64 + owner;
        unsigned v1 = dk[SKEW(p1)], v2 = dk[SKEW(p2)];
        unsigned long long c1 = ((unsigned long long)v1 << 32) | (unsigned)p1;
        unsigned long long c2 = ((unsigned long long)v2 << 32) | (unsigned)p2;
        unsigned long long cand = (c2 < c1) ? c2 : c1;
#pragma unroll
        for (int m = 1; m < 64; m <<= 1) {
            unsigned long long o = __shfl_xor(cand, m, 64);
            cand = (o < cand) ? o : cand;
        }
        if (l == owner) { bmin = (unsigned)(cand >> 32); bpos = (int)(cand & 0xFFFFFFFFu); }
        __syncthreads();
    }
}

// ---------------------------------------------------------------------------
// Kernel 5: gather + 1x1 conv (W: 128x67) + relu + max over group.
// Block = 256 thr = 4 waves = 4 queries; W rows live in registers.
// ---------------------------------------------------------------------------
__global__ __launch_bounds__(256, 2) void k_mlp(const float4* __restrict__ pts4,
                                                const float* __restrict__ feaT,
                                                const float4* __restrict__ qpts,
                                                const int* __restrict__ gidx,
                                                const float* __restrict__ W,
                                                float* __restrict__ out) {
    __shared__ float sm[8704];   // max(8576 W floats, 4*32*68 grouped floats)
    int t = threadIdx.x, l = t & 63, w = t >> 6;

    for (int i = t; i < 8576; i += 256) sm[i] = W[i];
    __syncthreads();
    float wa[68], wb[68];
#pragma unroll
    for (int c = 0; c < 68; c++) {
        wa[c] = (c < 67) ? sm[l * 67 + c] : 0.f;
        wb[c] = (c < 67) ? sm[(l + 64) * 67 + c] : 0.f;
    }
    __syncthreads();   // done reading W region before reuse

    int Q = blockIdx.x * 4 + w;
    int b = Q >> 10, s = Q & 1023;
    float4 q = qpts[Q];
    const int* gi = gidx + (long)Q * GG;
    int base = w * 2176;   // 32*68 per wave

    if (l < 32) {
        int idx = gi[l];
        float4 p = pts4[(long)b * NN + idx];
        float4 rc = make_float4(__fsub_rn(p.x, q.x), __fsub_rn(p.y, q.y),
                                __fsub_rn(p.z, q.z), 0.f);
        *(float4*)&sm[base + l * 68 + 64] = rc;
    }
    {
        int g = l >> 1, half = l & 1;
        int idx = gi[g];
        const float4* f4 = (const float4*)(feaT + ((long)b * NN + idx) * 64);
#pragma unroll
        for (int k = 0; k < 8; k++) {
            *(float4*)&sm[base + g * 68 + half * 32 + k * 4] = f4[half * 8 + k];
        }
    }
    __syncthreads();

    float m0 = -1e30f, m1 = -1e30f;
#pragma unroll 2
    for (int g = 0; g < GG; g++) {
        float a0 = 0.f, a1 = 0.f;
#pragma unroll
        for (int c4 = 0; c4 < 17; c4++) {
            float4 gv = *(float4*)&sm[base + g * 68 + c4 * 4];
            a0 = fmaf(gv.x, wa[4 * c4 + 0], a0);
            a0 = fmaf(gv.y, wa[4 * c4 + 1], a0);
            a0 = fmaf(gv.z, wa[4 * c4 + 2], a0);
            a0 = fmaf(gv.w, wa[4 * c4 + 3], a0);
            a1 = fmaf(gv.x, wb[4 * c4 + 0], a1);
            a1 = fmaf(gv.y, wb[4 * c4 + 1], a1);
            a1 = fmaf(gv.z, wb[4 * c4 + 2], a1);
            a1 = fmaf(gv.w, wb[4 * c4 + 3], a1);
        }
        m0 = fmaxf(m0, a0);
        m1 = fmaxf(m1, a1);
    }
    // outputs: (B,3,S) then (B,128,S); relu(max) == max(relu)
    out[49152 + ((long)b * 128 + l) * SS + s]      = fmaxf(m0, 0.f);
    out[49152 + ((long)b * 128 + l + 64) * SS + s] = fmaxf(m1, 0.f);
}

// ---------------------------------------------------------------------------
extern "C" void kernel_launch(void* const* d_in, const int* in_sizes, int n_in,
                              void* d_out, int out_size, void* d_ws, size_t ws_size,
                              hipStream_t stream) {
    const float* coor = (const float*)d_in[0];   // (16,3,8192)
    const float* fea  = (const float*)d_in[1];   // (16,64,8192)
    const float* Wm   = (const float*)d_in[2];   // (128,67)
    float* out = (float*)d_out;

    char* ws = (char*)d_ws;
    float4* pts4 = (float4*)ws;                               //  2 MB
    float*  feaT = (float*)(ws + 2097152);                    // 32 MB
    float4* qpts = (float4*)(ws + 2097152 + 33554432);        // 256 KB
    int*    gidx = (int*)(ws + 2097152 + 33554432 + 262144);  //  2 MB

    k_pts<<<(BB * NN) / 256, 256, 0, stream>>>(coor, pts4);
    k_tr<<<dim3(NN / 64, BB), 256, 0, stream>>>(fea, feaT);
    k_fps<<<BB, 512, 0, stream>>>(pts4, qpts, out);
    k_knn<<<BB * SS, 64, 0, stream>>>(pts4, qpts, gidx);
    k_mlp<<<(BB * SS) / 4, 256, 0, stream>>>(pts4, feaT, qpts, gidx, Wm, out);
}

// Round 4
// 1913.526 us; speedup vs baseline: 1.0279x; 1.0279x over previous
//
#include <hip/hip_runtime.h>
#include <hip/hip_bf16.h>

// Problem constants
#define BB 16
#define NN 8192
#define SS 1024
#define GG 32
// sortable(1.0f) = 0x3F800000 ^ 0x80000000
#define SORT_R2 0xBF800000u

typedef float v2f __attribute__((ext_vector_type(2)));

__device__ __forceinline__ unsigned sortable(float f) {
    unsigned u = __float_as_uint(f);
    return u ^ ((unsigned)(((int)u) >> 31) | 0x80000000u);
}

// u64 max-combine with a DPP-permuted copy. CTRL/RM compile-time.
// row_shr:n = 0x110|n, row_bcast15 = 0x142, row_bcast31 = 0x143.
template <int CTRL, int RM>
__device__ __forceinline__ unsigned long long dpp64_max(unsigned long long k) {
    int lo = (int)(unsigned)(k & 0xFFFFFFFFull);
    int hi = (int)(unsigned)(k >> 32);
    int plo = __builtin_amdgcn_update_dpp(lo, lo, CTRL, RM, 0xF, false);
    int phi = __builtin_amdgcn_update_dpp(hi, hi, CTRL, RM, 0xF, false);
    unsigned long long o =
        ((unsigned long long)(unsigned)phi << 32) | (unsigned)plo;
    return (o > k) ? o : k;
}

// ---------------------------------------------------------------------------
// Kernel 1: pack pts4[b][n] = {x, y, z, (x*x+y*y)+z*z}  (rn ops, no contraction)
// ---------------------------------------------------------------------------
__global__ __launch_bounds__(256) void k_pts(const float* __restrict__ coor,
                                             float4* __restrict__ pts4) {
    int i = blockIdx.x * 256 + threadIdx.x;   // 0 .. B*N-1
    int b = i >> 13, n = i & (NN - 1);
    const float* cb = coor + (long)b * 3 * NN;
    float x = cb[n], y = cb[NN + n], z = cb[2 * NN + n];
    float pn = __fadd_rn(__fadd_rn(__fmul_rn(x, x), __fmul_rn(y, y)), __fmul_rn(z, z));
    pts4[i] = make_float4(x, y, z, pn);
}

// ---------------------------------------------------------------------------
// Kernel 2: transpose fea (B,64,N) -> feaT (B,N,64)
// ---------------------------------------------------------------------------
__global__ __launch_bounds__(256) void k_tr(const float* __restrict__ fea,
                                            float* __restrict__ feaT) {
    __shared__ float tile[64][65];
    int b = blockIdx.y, n0 = blockIdx.x * 64;
    int t = threadIdx.x;
    int nl = t & 63, cb = t >> 6;
#pragma unroll
    for (int i = 0; i < 16; i++) {
        int c = cb * 16 + i;
        tile[nl][c] = fea[((long)b * 64 + c) * NN + n0 + nl];
    }
    __syncthreads();
    int cl = t & 63, nb = t >> 6;
#pragma unroll
    for (int i = 0; i < 16; i++) {
        int n = nb * 16 + i;
        feaT[((long)b * NN + n0 + n) * 64 + cl] = tile[n][cl];
    }
}

// ---------------------------------------------------------------------------
// Kernel 3: farthest point sampling. One block (512 thr) per batch.
// v4: single barrier per step (u64 value|idx reduction as in v2) BUT the
// wave-level butterfly is DPP (row_shr/row_bcast, ~80 cyc) instead of
// ds_bpermute shuffles (~350 cyc), and the per-thread argmax is a depth-4
// tree instead of a 16-deep serial chain. Distance math stays packed-v2f
// with contract(off): bit-exact rn mul/add vs reference. Tie semantics
// exact: max value, then lowest point index (8191-p in low word).
// ---------------------------------------------------------------------------
__global__ __launch_bounds__(512) void k_fps(const float4* __restrict__ pts4,
                                             float4* __restrict__ qpts,
                                             float* __restrict__ out) {
#pragma clang fp contract(off)
    __shared__ float xs[NN], ys[NN], zs[NN];
    __shared__ int scur[SS];
    __shared__ __align__(16) unsigned long long red[2][8];
    int b = blockIdx.x;
    int t = threadIdx.x;
    const float4* P = pts4 + (long)b * NN;

    // pair j, half h -> point p = t + (2j+h)*512
    v2f px[8], py[8], pz[8], dist[8];
#pragma unroll
    for (int j = 0; j < 8; j++) {
        int p0 = t + (2 * j) * 512;
        int p1 = t + (2 * j + 1) * 512;
        float4 a = P[p0];
        float4 c = P[p1];
        px[j] = v2f{a.x, c.x};
        py[j] = v2f{a.y, c.y};
        pz[j] = v2f{a.z, c.z};
        dist[j] = v2f{1e10f, 1e10f};
        xs[p0] = a.x; ys[p0] = a.y; zs[p0] = a.z;
        xs[p1] = c.x; ys[p1] = c.y; zs[p1] = c.z;
    }
    __syncthreads();

    int cur = 0;
    for (int s = 0; s < SS; s++) {
        float cx = xs[cur], cy = ys[cur], cz = zs[cur];
        if (t == 0) scur[s] = cur;
        v2f cx2 = v2f{cx, cx}, cy2 = v2f{cy, cy}, cz2 = v2f{cz, cz};
#pragma unroll
        for (int j = 0; j < 8; j++) {
            v2f dx = px[j] - cx2;
            v2f dy = py[j] - cy2;
            v2f dz = pz[j] - cz2;
            v2f xx = dx * dx;
            v2f yy = dy * dy;
            v2f zz = dz * dz;
            v2f sm = xx + yy;
            v2f d = sm + zz;
            dist[j].x = fminf(dist[j].x, d.x);
            dist[j].y = fminf(dist[j].y, d.y);
        }
        // per-thread argmax over 16 scalars: depth-4 tree, lowest index on tie
        // element order: (j,x) -> 2j, (j,y) -> 2j+1; point p = t + ord*512
        float va[8]; int ia[8];
#pragma unroll
        for (int i = 0; i < 8; i++) {
            float a = dist[i].x, bb2 = dist[i].y;
            bool c = bb2 > a;                 // strict: tie -> lower index (x)
            va[i] = c ? bb2 : a;
            ia[i] = 2 * i + (c ? 1 : 0);
        }
        float vb[4]; int ib[4];
#pragma unroll
        for (int i = 0; i < 4; i++) {
            bool c = va[2 * i + 1] > va[2 * i];
            vb[i] = c ? va[2 * i + 1] : va[2 * i];
            ib[i] = c ? ia[2 * i + 1] : ia[2 * i];
        }
        float vc0, vc1; int ic0, ic1;
        {
            bool c = vb[1] > vb[0];
            vc0 = c ? vb[1] : vb[0]; ic0 = c ? ib[1] : ib[0];
            bool c2 = vb[3] > vb[2];
            vc1 = c2 ? vb[3] : vb[2]; ic1 = c2 ? ib[3] : ib[2];
        }
        bool cf = vc1 > vc0;
        float bv = cf ? vc1 : vc0;
        int bj = cf ? ic1 : ic0;
        int bp = t + bj * 512;
        // dist >= 0 so float bits monotonic; (8191-p) => max picks min p on ties
        unsigned long long key =
            ((unsigned long long)__float_as_uint(bv) << 32) | (unsigned)(8191 - bp);
        // 64-lane DPP max reduction; result lands in lane 63 of each wave
        key = dpp64_max<0x111, 0xF>(key);   // row_shr:1
        key = dpp64_max<0x112, 0xF>(key);   // row_shr:2
        key = dpp64_max<0x114, 0xF>(key);   // row_shr:4
        key = dpp64_max<0x118, 0xF>(key);   // row_shr:8
        key = dpp64_max<0x142, 0xA>(key);   // row_bcast:15 (rows 1,3)
        key = dpp64_max<0x143, 0xC>(key);   // row_bcast:31 (rows 2,3)
        int par = s & 1;
        if ((t & 63) == 63) red[par][t >> 6] = key;
        __syncthreads();
        unsigned long long best = red[par][0];
#pragma unroll
        for (int w = 1; w < 8; w++) {
            unsigned long long o = red[par][w];
            best = (o > best) ? o : best;
        }
        cur = 8191 - (int)(best & 0xFFFFFFFFu);
    }
    __syncthreads();

    // epilogue: write new_coor (B,3,S) and query points from recorded indices
#pragma unroll
    for (int s = t; s < SS; s += 512) {
        int c = scur[s];
        float cx = xs[c], cy = ys[c], cz = zs[c];
        out[(long)b * 3 * SS + s]          = cx;
        out[(long)b * 3 * SS + SS + s]     = cy;
        out[(long)b * 3 * SS + 2 * SS + s] = cz;
        float qn = __fadd_rn(__fadd_rn(__fmul_rn(cx, cx), __fmul_rn(cy, cy)),
                             __fmul_rn(cz, cz));
        qpts[(long)b * SS + s] = make_float4(cx, cy, cz, qn);
    }
}

// ---------------------------------------------------------------------------
// Kernel 4: exact 32-NN per query (one wave per query), reference formula
// d = (qn - 2*dot) + pn; stable tie-break by index (matches lax.top_k);
// radius filter d > 1.0 -> replace with nearest index.
// ---------------------------------------------------------------------------
#define SKEW(p) ((p) + ((p) >> 5))
__global__ __launch_bounds__(64) void k_knn(const float4* __restrict__ pts4,
                                            const float4* __restrict__ qpts,
                                            int* __restrict__ gidx) {
    __shared__ unsigned dk[NN + NN / 32];   // 8448
    int Q = blockIdx.x;                      // b*1024 + s
    int b = Q >> 10;
    int l = threadIdx.x;
    float4 q = qpts[Q];
    const float4* P = pts4 + (long)b * NN;

    unsigned bmin = 0xFFFFFFFFu;
    int bpos = 0;
    for (int j = 0; j < 128; j++) {
        int p = j * 64 + l;
        float4 v = P[p];
        float dot = __fadd_rn(__fadd_rn(__fmul_rn(q.x, v.x), __fmul_rn(q.y, v.y)),
                              __fmul_rn(q.z, v.z));
        float d = __fadd_rn(__fsub_rn(q.w, __fmul_rn(2.0f, dot)), v.w);
        unsigned u = sortable(d);
        dk[SKEW(p)] = u;
        if (u < bmin) { bmin = u; bpos = p; }   // ascending p -> earliest index on tie
    }
    __syncthreads();

    int pos0 = 0;
    for (int k = 0; k < GG; k++) {
        unsigned long long key = ((unsigned long long)bmin << 32) | (unsigned)bpos;
#pragma unroll
        for (int m = 1; m < 64; m <<= 1) {
            unsigned long long o = __shfl_xor(key, m, 64);
            key = (o < key) ? o : key;
        }
        int kpos = (int)(key & 0xFFFFFFFFu);
        unsigned kval = (unsigned)(key >> 32);
        if (k == 0) pos0 = kpos;
        if (l == 0) gidx[(long)Q * GG + k] = (kval > SORT_R2) ? pos0 : kpos;
        int owner = kpos & 63;
        if (l == owner) dk[SKEW(kpos)] = 0xFFFFFFFFu;   // invalidate popped slot
        __syncthreads();
        // cooperative rescan of owner's column (its 128 points)
        int p1 = l * 64 + owner;
        int p2 = (l + 64) * 64 + owner;
        unsigned v1 = dk[SKEW(p1)], v2 = dk[SKEW(p2)];
        unsigned long long c1 = ((unsigned long long)v1 << 32) | (unsigned)p1;
        unsigned long long c2 = ((unsigned long long)v2 << 32) | (unsigned)p2;
        unsigned long long cand = (c2 < c1) ? c2 : c1;
#pragma unroll
        for (int m = 1; m < 64; m <<= 1) {
            unsigned long long o = __shfl_xor(cand, m, 64);
            cand = (o < cand) ? o : cand;
        }
        if (l == owner) { bmin = (unsigned)(cand >> 32); bpos = (int)(cand & 0xFFFFFFFFu); }
        __syncthreads();
    }
}

// ---------------------------------------------------------------------------
// Kernel 5: gather + 1x1 conv (W: 128x67) + relu + max over group.
// Block = 256 thr = 4 waves = 4 queries; W rows live in registers.
// ---------------------------------------------------------------------------
__global__ __launch_bounds__(256, 2) void k_mlp(const float4* __restrict__ pts4,
                                                const float* __restrict__ feaT,
                                                const float4* __restrict__ qpts,
                                                const int* __restrict__ gidx,
                                                const float* __restrict__ W,
                                                float* __restrict__ out) {
    __shared__ float sm[8704];   // max(8576 W floats, 4*32*68 grouped floats)
    int t = threadIdx.x, l = t & 63, w = t >> 6;

    for (int i = t; i < 8576; i += 256) sm[i] = W[i];
    __syncthreads();
    float wa[68], wb[68];
#pragma unroll
    for (int c = 0; c < 68; c++) {
        wa[c] = (c < 67) ? sm[l * 67 + c] : 0.f;
        wb[c] = (c < 67) ? sm[(l + 64) * 67 + c] : 0.f;
    }
    __syncthreads();   // done reading W region before reuse

    int Q = blockIdx.x * 4 + w;
    int b = Q >> 10, s = Q & 1023;
    float4 q = qpts[Q];
    const int* gi = gidx + (long)Q * GG;
    int base = w * 2176;   // 32*68 per wave

    if (l < 32) {
        int idx = gi[l];
        float4 p = pts4[(long)b * NN + idx];
        float4 rc = make_float4(__fsub_rn(p.x, q.x), __fsub_rn(p.y, q.y),
                                __fsub_rn(p.z, q.z), 0.f);
        *(float4*)&sm[base + l * 68 + 64] = rc;
    }
    {
        int g = l >> 1, half = l & 1;
        int idx = gi[g];
        const float4* f4 = (const float4*)(feaT + ((long)b * NN + idx) * 64);
#pragma unroll
        for (int k = 0; k < 8; k++) {
            *(float4*)&sm[base + g * 68 + half * 32 + k * 4] = f4[half * 8 + k];
        }
    }
    __syncthreads();

    float m0 = -1e30f, m1 = -1e30f;
#pragma unroll 2
    for (int g = 0; g < GG; g++) {
        float a0 = 0.f, a1 = 0.f;
#pragma unroll
        for (int c4 = 0; c4 < 17; c4++) {
            float4 gv = *(float4*)&sm[base + g * 68 + c4 * 4];
            a0 = fmaf(gv.x, wa[4 * c4 + 0], a0);
            a0 = fmaf(gv.y, wa[4 * c4 + 1], a0);
            a0 = fmaf(gv.z, wa[4 * c4 + 2], a0);
            a0 = fmaf(gv.w, wa[4 * c4 + 3], a0);
            a1 = fmaf(gv.x, wb[4 * c4 + 0], a1);
            a1 = fmaf(gv.y, wb[4 * c4 + 1], a1);
            a1 = fmaf(gv.z, wb[4 * c4 + 2], a1);
            a1 = fmaf(gv.w, wb[4 * c4 + 3], a1);
        }
        m0 = fmaxf(m0, a0);
        m1 = fmaxf(m1, a1);
    }
    // outputs: (B,3,S) then (B,128,S); relu(max) == max(relu)
    out[49152 + ((long)b * 128 + l) * SS + s]      = fmaxf(m0, 0.f);
    out[49152 + ((long)b * 128 + l + 64) * SS + s] = fmaxf(m1, 0.f);
}

// ---------------------------------------------------------------------------
extern "C" void kernel_launch(void* const* d_in, const int* in_sizes, int n_in,
                              void* d_out, int out_size, void* d_ws, size_t ws_size,
                              hipStream_t stream) {
    const float* coor = (const float*)d_in[0];   // (16,3,8192)
    const float* fea  = (const float*)d_in[1];   // (16,64,8192)
    const float* Wm   = (const float*)d_in[2];   // (128,67)
    float* out = (float*)d_out;

    char* ws = (char*)d_ws;
    float4* pts4 = (float4*)ws;                               //  2 MB
    float*  feaT = (float*)(ws + 2097152);                    // 32 MB
    float4* qpts = (float4*)(ws + 2097152 + 33554432);        // 256 KB
    int*    gidx = (int*)(ws + 2097152 + 33554432 + 262144);  //  2 MB

    k_pts<<<(BB * NN) / 256, 256, 0, stream>>>(coor, pts4);
    k_tr<<<dim3(NN / 64, BB), 256, 0, stream>>>(fea, feaT);
    k_fps<<<BB, 512, 0, stream>>>(pts4, qpts, out);
    k_knn<<<BB * SS, 64, 0, stream>>>(pts4, qpts, gidx);
    k_mlp<<<(BB * SS) / 4, 256, 0, stream>>>(pts4, feaT, qpts, gidx, Wm, out);
}

// Round 5
// 1667.247 us; speedup vs baseline: 1.1797x; 1.1477x over previous
//
#include <hip/hip_runtime.h>
#include <hip/hip_bf16.h>

// Problem constants
#define BB 16
#define NN 8192
#define SS 1024
#define GG 32
// sortable(1.0f) = 0x3F800000 ^ 0x80000000
#define SORT_R2 0xBF800000u

typedef float v2f __attribute__((ext_vector_type(2)));

__device__ __forceinline__ unsigned sortable(float f) {
    unsigned u = __float_as_uint(f);
    return u ^ ((unsigned)(((int)u) >> 31) | 0x80000000u);
}

// f32 max-combine with a DPP-permuted copy (2 slots: v_mov_dpp + v_max_f32).
// row_shr:n = 0x110|n, row_bcast15 = 0x142, row_bcast31 = 0x143.
template <int CTRL, int RM>
__device__ __forceinline__ float dpp_maxf(float v) {
    int i = __float_as_int(v);
    int p = __builtin_amdgcn_update_dpp(i, i, CTRL, RM, 0xF, false);
    return fmaxf(v, __int_as_float(p));
}

__device__ __forceinline__ float fmax3(float a, float b, float c) {
    return fmaxf(fmaxf(a, b), c);   // fuses to v_max3_f32
}

// ---------------------------------------------------------------------------
// Kernel 1: pack pts4[b][n] = {x, y, z, (x*x+y*y)+z*z}  (rn ops, no contraction)
// ---------------------------------------------------------------------------
__global__ __launch_bounds__(256) void k_pts(const float* __restrict__ coor,
                                             float4* __restrict__ pts4) {
    int i = blockIdx.x * 256 + threadIdx.x;   // 0 .. B*N-1
    int b = i >> 13, n = i & (NN - 1);
    const float* cb = coor + (long)b * 3 * NN;
    float x = cb[n], y = cb[NN + n], z = cb[2 * NN + n];
    float pn = __fadd_rn(__fadd_rn(__fmul_rn(x, x), __fmul_rn(y, y)), __fmul_rn(z, z));
    pts4[i] = make_float4(x, y, z, pn);
}

// ---------------------------------------------------------------------------
// Kernel 2: transpose fea (B,64,N) -> feaT (B,N,64)
// ---------------------------------------------------------------------------
__global__ __launch_bounds__(256) void k_tr(const float* __restrict__ fea,
                                            float* __restrict__ feaT) {
    __shared__ float tile[64][65];
    int b = blockIdx.y, n0 = blockIdx.x * 64;
    int t = threadIdx.x;
    int nl = t & 63, cb = t >> 6;
#pragma unroll
    for (int i = 0; i < 16; i++) {
        int c = cb * 16 + i;
        tile[nl][c] = fea[((long)b * 64 + c) * NN + n0 + nl];
    }
    __syncthreads();
    int cl = t & 63, nb = t >> 6;
#pragma unroll
    for (int i = 0; i < 16; i++) {
        int n = nb * 16 + i;
        feaT[((long)b * NN + n0 + n) * 64 + cl] = tile[n][cl];
    }
}

// ---------------------------------------------------------------------------
// Kernel 3: farthest point sampling. One block (512 thr) per batch.
// v5: packed v2f distance update (R3's measured VALU-work win) + value-only
// f32 DPP wave max (12 slots vs 30 for u64) + index resolution via LDS
// atomicMin performed ONLY by threads whose local max equals the global max
// (typically one thread/block) — the per-thread index machinery is gone from
// the common path. Two cheap barriers/step. Distance math contract(off),
// bit-exact rn ops; tie semantics exact (lowest flat index wins).
// ---------------------------------------------------------------------------
__global__ __launch_bounds__(512) void k_fps(const float4* __restrict__ pts4,
                                             float4* __restrict__ qpts,
                                             float* __restrict__ out) {
#pragma clang fp contract(off)
    __shared__ float xs[NN], ys[NN], zs[NN];
    __shared__ int scur[SS];
    __shared__ __align__(16) float redv[2][8];
    __shared__ int sidx[2];
    int b = blockIdx.x;
    int t = threadIdx.x;
    const float4* P = pts4 + (long)b * NN;

    // pair j, half h -> point p = t + (2j+h)*512
    v2f px[8], py[8], pz[8], dist[8];
#pragma unroll
    for (int j = 0; j < 8; j++) {
        int p0 = t + (2 * j) * 512;
        int p1 = t + (2 * j + 1) * 512;
        float4 a = P[p0];
        float4 c = P[p1];
        px[j] = v2f{a.x, c.x};
        py[j] = v2f{a.y, c.y};
        pz[j] = v2f{a.z, c.z};
        dist[j] = v2f{1e10f, 1e10f};
        xs[p0] = a.x; ys[p0] = a.y; zs[p0] = a.z;
        xs[p1] = c.x; ys[p1] = c.y; zs[p1] = c.z;
    }
    if (t == 0) { sidx[0] = 0x7FFFFFFF; sidx[1] = 0x7FFFFFFF; }
    __syncthreads();

    int cur = 0;
    for (int s = 0; s < SS; s++) {
        int par = s & 1;
        float cx = xs[cur], cy = ys[cur], cz = zs[cur];
        if (t == 0) scur[s] = cur;
        v2f cx2 = v2f{cx, cx}, cy2 = v2f{cy, cy}, cz2 = v2f{cz, cz};
#pragma unroll
        for (int j = 0; j < 8; j++) {
            v2f dx = px[j] - cx2;
            v2f dy = py[j] - cy2;
            v2f dz = pz[j] - cz2;
            v2f xx = dx * dx;
            v2f yy = dy * dy;
            v2f zz = dz * dz;
            v2f sm = xx + yy;
            v2f d = sm + zz;
            dist[j] = __builtin_elementwise_min(dist[j], d);
        }
        // value-only per-thread max: packed tree (7 pk-max) + final scalar
        v2f m01 = __builtin_elementwise_max(dist[0], dist[1]);
        v2f m23 = __builtin_elementwise_max(dist[2], dist[3]);
        v2f m45 = __builtin_elementwise_max(dist[4], dist[5]);
        v2f m67 = __builtin_elementwise_max(dist[6], dist[7]);
        v2f m03 = __builtin_elementwise_max(m01, m23);
        v2f m47 = __builtin_elementwise_max(m45, m67);
        v2f m07 = __builtin_elementwise_max(m03, m47);
        float bv = fmaxf(m07.x, m07.y);
        // 64-lane DPP f32 max; result lands in lane 63 of each wave
        float wv = bv;
        wv = dpp_maxf<0x111, 0xF>(wv);   // row_shr:1
        wv = dpp_maxf<0x112, 0xF>(wv);   // row_shr:2
        wv = dpp_maxf<0x114, 0xF>(wv);   // row_shr:4
        wv = dpp_maxf<0x118, 0xF>(wv);   // row_shr:8
        wv = dpp_maxf<0x142, 0xA>(wv);   // row_bcast:15 (rows 1,3)
        wv = dpp_maxf<0x143, 0xC>(wv);   // row_bcast:31 (rows 2,3)
        if ((t & 63) == 63) redv[par][t >> 6] = wv;
        __syncthreads();                 // barrier 1
        float4 r0 = *(const float4*)redv[par];
        float4 r1 = *(const float4*)(redv[par] + 4);
        float gmax = fmaxf(fmax3(r0.x, r0.y, r0.z),
                           fmax3(r0.w, fmax3(r1.x, r1.y, r1.z), r1.w));
        // reset the OTHER slot (last used at s-1, needed at s+1); barrier 2
        // separates this write from s+1's atomics.
        if (t == 0) sidx[1 - par] = 0x7FFFFFFF;
        if (bv == gmax) {
            // rare path (usually 1 thread/block): lowest matching ord
            int jj = 15;
#pragma unroll
            for (int j = 7; j >= 0; j--) {
                jj = (dist[j].y == gmax) ? (2 * j + 1) : jj;
                jj = (dist[j].x == gmax) ? (2 * j) : jj;
            }
            atomicMin(&sidx[par], t + jj * 512);
        }
        __syncthreads();                 // barrier 2
        cur = sidx[par];
    }
    __syncthreads();

    // epilogue: write new_coor (B,3,S) and query points from recorded indices
#pragma unroll
    for (int s = t; s < SS; s += 512) {
        int c = scur[s];
        float cx = xs[c], cy = ys[c], cz = zs[c];
        out[(long)b * 3 * SS + s]          = cx;
        out[(long)b * 3 * SS + SS + s]     = cy;
        out[(long)b * 3 * SS + 2 * SS + s] = cz;
        float qn = __fadd_rn(__fadd_rn(__fmul_rn(cx, cx), __fmul_rn(cy, cy)),
                             __fmul_rn(cz, cz));
        qpts[(long)b * SS + s] = make_float4(cx, cy, cz, qn);
    }
}

// ---------------------------------------------------------------------------
// Kernel 4: exact 32-NN per query (one wave per query), reference formula
// d = (qn - 2*dot) + pn; stable tie-break by index (matches lax.top_k);
// radius filter d > 1.0 -> replace with nearest index.
// ---------------------------------------------------------------------------
#define SKEW(p) ((p) + ((p) >> 5))
__global__ __launch_bounds__(64) void k_knn(const float4* __restrict__ pts4,
                                            const float4* __restrict__ qpts,
                                            int* __restrict__ gidx) {
    __shared__ unsigned dk[NN + NN / 32];   // 8448
    int Q = blockIdx.x;                      // b*1024 + s
    int b = Q >> 10;
    int l = threadIdx.x;
    float4 q = qpts[Q];
    const float4* P = pts4 + (long)b * NN;

    unsigned bmin = 0xFFFFFFFFu;
    int bpos = 0;
    for (int j = 0; j < 128; j++) {
        int p = j * 64 + l;
        float4 v = P[p];
        float dot = __fadd_rn(__fadd_rn(__fmul_rn(q.x, v.x), __fmul_rn(q.y, v.y)),
                              __fmul_rn(q.z, v.z));
        float d = __fadd_rn(__fsub_rn(q.w, __fmul_rn(2.0f, dot)), v.w);
        unsigned u = sortable(d);
        dk[SKEW(p)] = u;
        if (u < bmin) { bmin = u; bpos = p; }   // ascending p -> earliest index on tie
    }
    __syncthreads();

    int pos0 = 0;
    for (int k = 0; k < GG; k++) {
        unsigned long long key = ((unsigned long long)bmin << 32) | (unsigned)bpos;
#pragma unroll
        for (int m = 1; m < 64; m <<= 1) {
            unsigned long long o = __shfl_xor(key, m, 64);
            key = (o < key) ? o : key;
        }
        int kpos = (int)(key & 0xFFFFFFFFu);
        unsigned kval = (unsigned)(key >> 32);
        if (k == 0) pos0 = kpos;
        if (l == 0) gidx[(long)Q * GG + k] = (kval > SORT_R2) ? pos0 : kpos;
        int owner = kpos & 63;
        if (l == owner) dk[SKEW(kpos)] = 0xFFFFFFFFu;   // invalidate popped slot
        __syncthreads();
        // cooperative rescan of owner's column (its 128 points)
        int p1 = l * 64 + owner;
        int p2 = (l + 64) * 64 + owner;
        unsigned v1 = dk[SKEW(p1)], v2 = dk[SKEW(p2)];
        unsigned long long c1 = ((unsigned long long)v1 << 32) | (unsigned)p1;
        unsigned long long c2 = ((unsigned long long)v2 << 32) | (unsigned)p2;
        unsigned long long cand = (c2 < c1) ? c2 : c1;
#pragma unroll
        for (int m = 1; m < 64; m <<= 1) {
            unsigned long long o = __shfl_xor(cand, m, 64);
            cand = (o < cand) ? o : cand;
        }
        if (l == owner) { bmin = (unsigned)(cand >> 32); bpos = (int)(cand & 0xFFFFFFFFu); }
        __syncthreads();
    }
}

// ---------------------------------------------------------------------------
// Kernel 5: gather + 1x1 conv (W: 128x67) + relu + max over group.
// Block = 256 thr = 4 waves = 4 queries; W rows live in registers.
// ---------------------------------------------------------------------------
__global__ __launch_bounds__(256, 2) void k_mlp(const float4* __restrict__ pts4,
                                                const float* __restrict__ feaT,
                                                const float4* __restrict__ qpts,
                                                const int* __restrict__ gidx,
                                                const float* __restrict__ W,
                                                float* __restrict__ out) {
    __shared__ float sm[8704];   // max(8576 W floats, 4*32*68 grouped floats)
    int t = threadIdx.x, l = t & 63, w = t >> 6;

    for (int i = t; i < 8576; i += 256) sm[i] = W[i];
    __syncthreads();
    float wa[68], wb[68];
#pragma unroll
    for (int c = 0; c < 68; c++) {
        wa[c] = (c < 67) ? sm[l * 67 + c] : 0.f;
        wb[c] = (c < 67) ? sm[(l + 64) * 67 + c] : 0.f;
    }
    __syncthreads();   // done reading W region before reuse

    int Q = blockIdx.x * 4 + w;
    int b = Q >> 10, s = Q & 1023;
    float4 q = qpts[Q];
    const int* gi = gidx + (long)Q * GG;
    int base = w * 2176;   // 32*68 per wave

    if (l < 32) {
        int idx = gi[l];
        float4 p = pts4[(long)b * NN + idx];
        float4 rc = make_float4(__fsub_rn(p.x, q.x), __fsub_rn(p.y, q.y),
                                __fsub_rn(p.z, q.z), 0.f);
        *(float4*)&sm[base + l * 68 + 64] = rc;
    }
    {
        int g = l >> 1, half = l & 1;
        int idx = gi[g];
        const float4* f4 = (const float4*)(feaT + ((long)b * NN + idx) * 64);
#pragma unroll
        for (int k = 0; k < 8; k++) {
            *(float4*)&sm[base + g * 68 + half * 32 + k * 4] = f4[half * 8 + k];
        }
    }
    __syncthreads();

    float m0 = -1e30f, m1 = -1e30f;
#pragma unroll 2
    for (int g = 0; g < GG; g++) {
        float a0 = 0.f, a1 = 0.f;
#pragma unroll
        for (int c4 = 0; c4 < 17; c4++) {
            float4 gv = *(float4*)&sm[base + g * 68 + c4 * 4];
            a0 = fmaf(gv.x, wa[4 * c4 + 0], a0);
            a0 = fmaf(gv.y, wa[4 * c4 + 1], a0);
            a0 = fmaf(gv.z, wa[4 * c4 + 2], a0);
            a0 = fmaf(gv.w, wa[4 * c4 + 3], a0);
            a1 = fmaf(gv.x, wb[4 * c4 + 0], a1);
            a1 = fmaf(gv.y, wb[4 * c4 + 1], a1);
            a1 = fmaf(gv.z, wb[4 * c4 + 2], a1);
            a1 = fmaf(gv.w, wb[4 * c4 + 3], a1);
        }
        m0 = fmaxf(m0, a0);
        m1 = fmaxf(m1, a1);
    }
    // outputs: (B,3,S) then (B,128,S); relu(max) == max(relu)
    out[49152 + ((long)b * 128 + l) * SS + s]      = fmaxf(m0, 0.f);
    out[49152 + ((long)b * 128 + l + 64) * SS + s] = fmaxf(m1, 0.f);
}

// ---------------------------------------------------------------------------
extern "C" void kernel_launch(void* const* d_in, const int* in_sizes, int n_in,
                              void* d_out, int out_size, void* d_ws, size_t ws_size,
                              hipStream_t stream) {
    const float* coor = (const float*)d_in[0];   // (16,3,8192)
    const float* fea  = (const float*)d_in[1];   // (16,64,8192)
    const float* Wm   = (const float*)d_in[2];   // (128,67)
    float* out = (float*)d_out;

    char* ws = (char*)d_ws;
    float4* pts4 = (float4*)ws;                               //  2 MB
    float*  feaT = (float*)(ws + 2097152);                    // 32 MB
    float4* qpts = (float4*)(ws + 2097152 + 33554432);        // 256 KB
    int*    gidx = (int*)(ws + 2097152 + 33554432 + 262144);  //  2 MB

    k_pts<<<(BB * NN) / 256, 256, 0, stream>>>(coor, pts4);
    k_tr<<<dim3(NN / 64, BB), 256, 0, stream>>>(fea, feaT);
    k_fps<<<BB, 512, 0, stream>>>(pts4, qpts, out);
    k_knn<<<BB * SS, 64, 0, stream>>>(pts4, qpts, gidx);
    k_mlp<<<(BB * SS) / 4, 256, 0, stream>>>(pts4, feaT, qpts, gidx, Wm, out);
}

// Round 6
// 1579.740 us; speedup vs baseline: 1.2451x; 1.0554x over previous
//
#include <hip/hip_runtime.h>
#include <hip/hip_bf16.h>

// Problem constants
#define BB 16
#define NN 8192
#define SS 1024
#define GG 32
// sortable(1.0f) = 0x3F800000 ^ 0x80000000
#define SORT_R2 0xBF800000u

typedef float v2f __attribute__((ext_vector_type(2)));

__device__ __forceinline__ unsigned sortable(float f) {
    unsigned u = __float_as_uint(f);
    return u ^ ((unsigned)(((int)u) >> 31) | 0x80000000u);
}

// f32 max-combine with a DPP-permuted copy (2 slots: v_mov_dpp + v_max_f32).
// row_shr:n = 0x110|n, row_bcast15 = 0x142, row_bcast31 = 0x143.
template <int CTRL, int RM>
__device__ __forceinline__ float dpp_maxf(float v) {
    int i = __float_as_int(v);
    int p = __builtin_amdgcn_update_dpp(i, i, CTRL, RM, 0xF, false);
    return fmaxf(v, __int_as_float(p));
}

// u32 min-combine with a DPP-permuted copy (2 slots).
template <int CTRL, int RM>
__device__ __forceinline__ unsigned dpp_minu(unsigned v) {
    int p = __builtin_amdgcn_update_dpp((int)v, (int)v, CTRL, RM, 0xF, false);
    return min(v, (unsigned)p);
}

__device__ __forceinline__ float fmax3(float a, float b, float c) {
    return fmaxf(fmaxf(a, b), c);   // fuses to v_max3_f32
}

// ---------------------------------------------------------------------------
// Kernel 1: pack pts4[b][n] = {x, y, z, (x*x+y*y)+z*z}  (rn ops, no contraction)
// ---------------------------------------------------------------------------
__global__ __launch_bounds__(256) void k_pts(const float* __restrict__ coor,
                                             float4* __restrict__ pts4) {
    int i = blockIdx.x * 256 + threadIdx.x;   // 0 .. B*N-1
    int b = i >> 13, n = i & (NN - 1);
    const float* cb = coor + (long)b * 3 * NN;
    float x = cb[n], y = cb[NN + n], z = cb[2 * NN + n];
    float pn = __fadd_rn(__fadd_rn(__fmul_rn(x, x), __fmul_rn(y, y)), __fmul_rn(z, z));
    pts4[i] = make_float4(x, y, z, pn);
}

// ---------------------------------------------------------------------------
// Kernel 2: transpose fea (B,64,N) -> feaT (B,N,64)
// ---------------------------------------------------------------------------
__global__ __launch_bounds__(256) void k_tr(const float* __restrict__ fea,
                                            float* __restrict__ feaT) {
    __shared__ float tile[64][65];
    int b = blockIdx.y, n0 = blockIdx.x * 64;
    int t = threadIdx.x;
    int nl = t & 63, cb = t >> 6;
#pragma unroll
    for (int i = 0; i < 16; i++) {
        int c = cb * 16 + i;
        tile[nl][c] = fea[((long)b * 64 + c) * NN + n0 + nl];
    }
    __syncthreads();
    int cl = t & 63, nb = t >> 6;
#pragma unroll
    for (int i = 0; i < 16; i++) {
        int n = nb * 16 + i;
        feaT[((long)b * NN + n0 + n) * 64 + cl] = tile[n][cl];
    }
}

// ---------------------------------------------------------------------------
// Kernel 3: farthest point sampling. One block (512 thr) per batch.
// v6: ONE barrier per step. Value-only f32 DPP wave max (kept from v5);
// lanes matching their wave max compute their lowest matching index and
// issue LDS atomicMax of (dist_bits<<32)|(8191-p) — max picks (max dist,
// then lowest p): exact jnp.argmax tie semantics. gkey triple-buffered so
// the reset is always barrier-separated from readers. Distance math
// contract(off) packed v2f: bit-exact rn ops vs reference.
// ---------------------------------------------------------------------------
__global__ __launch_bounds__(512) void k_fps(const float4* __restrict__ pts4,
                                             float4* __restrict__ qpts,
                                             float* __restrict__ out) {
#pragma clang fp contract(off)
    __shared__ float xs[NN], ys[NN], zs[NN];
    __shared__ int scur[SS];
    __shared__ unsigned long long gkey[3];
    int b = blockIdx.x;
    int t = threadIdx.x;
    const float4* P = pts4 + (long)b * NN;

    // pair j, half h -> point p = t + (2j+h)*512
    v2f px[8], py[8], pz[8], dist[8];
#pragma unroll
    for (int j = 0; j < 8; j++) {
        int p0 = t + (2 * j) * 512;
        int p1 = t + (2 * j + 1) * 512;
        float4 a = P[p0];
        float4 c = P[p1];
        px[j] = v2f{a.x, c.x};
        py[j] = v2f{a.y, c.y};
        pz[j] = v2f{a.z, c.z};
        dist[j] = v2f{1e10f, 1e10f};
        xs[p0] = a.x; ys[p0] = a.y; zs[p0] = a.z;
        xs[p1] = c.x; ys[p1] = c.y; zs[p1] = c.z;
    }
    if (t < 3) gkey[t] = 0ull;
    __syncthreads();

    int cur = 0;
    int par = 0;
    for (int s = 0; s < SS; s++) {
        float cx = xs[cur], cy = ys[cur], cz = zs[cur];
        int nxt = (par == 2) ? 0 : par + 1;
        if (t == 0) {
            scur[s] = cur;
            gkey[nxt] = 0ull;   // slot for step s+1; its last readers were
                                // barrier-separated (read at end of s-2)
        }
        v2f cx2 = v2f{cx, cx}, cy2 = v2f{cy, cy}, cz2 = v2f{cz, cz};
#pragma unroll
        for (int j = 0; j < 8; j++) {
            v2f dx = px[j] - cx2;
            v2f dy = py[j] - cy2;
            v2f dz = pz[j] - cz2;
            v2f xx = dx * dx;
            v2f yy = dy * dy;
            v2f zz = dz * dz;
            v2f sm = xx + yy;
            v2f d = sm + zz;
            dist[j] = __builtin_elementwise_min(dist[j], d);
        }
        // value-only per-thread max: packed tree (7 pk-max) + final scalar
        v2f m01 = __builtin_elementwise_max(dist[0], dist[1]);
        v2f m23 = __builtin_elementwise_max(dist[2], dist[3]);
        v2f m45 = __builtin_elementwise_max(dist[4], dist[5]);
        v2f m67 = __builtin_elementwise_max(dist[6], dist[7]);
        v2f m03 = __builtin_elementwise_max(m01, m23);
        v2f m47 = __builtin_elementwise_max(m45, m67);
        v2f m07 = __builtin_elementwise_max(m03, m47);
        float bv = fmaxf(m07.x, m07.y);
        // 64-lane DPP f32 max; full-wave max lands in lane 63
        float wv = bv;
        wv = dpp_maxf<0x111, 0xF>(wv);   // row_shr:1
        wv = dpp_maxf<0x112, 0xF>(wv);   // row_shr:2
        wv = dpp_maxf<0x114, 0xF>(wv);   // row_shr:4
        wv = dpp_maxf<0x118, 0xF>(wv);   // row_shr:8
        wv = dpp_maxf<0x142, 0xA>(wv);   // row_bcast:15 (rows 1,3)
        wv = dpp_maxf<0x143, 0xC>(wv);   // row_bcast:31 (rows 2,3)
        float wm = __int_as_float(__builtin_amdgcn_readlane(__float_as_int(wv), 63));
        if (bv == wm) {
            // >=1 lane per wave; usually 1 in the whole block holds gmax.
            int jj = 15;
#pragma unroll
            for (int j = 7; j >= 0; j--) {
                jj = (dist[j].y == bv) ? (2 * j + 1) : jj;
                jj = (dist[j].x == bv) ? (2 * j) : jj;
            }
            int p = t + jj * 512;
            unsigned long long key =
                ((unsigned long long)__float_as_uint(bv) << 32) | (unsigned)(8191 - p);
            atomicMax(&gkey[par], key);
        }
        __syncthreads();
        cur = 8191 - (int)((unsigned)(gkey[par] & 0xFFFFFFFFull));
        par = nxt;
    }
    __syncthreads();

    // epilogue: write new_coor (B,3,S) and query points from recorded indices
#pragma unroll
    for (int s = t; s < SS; s += 512) {
        int c = scur[s];
        float cx = xs[c], cy = ys[c], cz = zs[c];
        out[(long)b * 3 * SS + s]          = cx;
        out[(long)b * 3 * SS + SS + s]     = cy;
        out[(long)b * 3 * SS + 2 * SS + s] = cz;
        float qn = __fadd_rn(__fadd_rn(__fmul_rn(cx, cx), __fmul_rn(cy, cy)),
                             __fmul_rn(cz, cz));
        qpts[(long)b * SS + s] = make_float4(cx, cy, cz, qn);
    }
}

// ---------------------------------------------------------------------------
// Kernel 4: exact 32-NN per query (one wave per query), reference formula
// d = (qn - 2*dot) + pn; stable tie-break by index (matches lax.top_k);
// radius filter d > 1.0 -> replace with nearest index.
// v2: pops use u32 DPP min + readlane + ballot (fast path); exact u64
// butterfly fallback when multiple lanes tie. gidx buffered in registers,
// one coalesced store in the epilogue (no per-pop global stores).
// ---------------------------------------------------------------------------
#define SKEW(p) ((p) + ((p) >> 5))
__global__ __launch_bounds__(64) void k_knn(const float4* __restrict__ pts4,
                                            const float4* __restrict__ qpts,
                                            int* __restrict__ gidx) {
    __shared__ unsigned dk[NN + NN / 32];   // 8448
    int Q = blockIdx.x;                      // b*1024 + s
    int b = Q >> 10;
    int l = threadIdx.x;
    float4 q = qpts[Q];
    const float4* P = pts4 + (long)b * NN;

    unsigned bmin = 0xFFFFFFFFu;
    int bpos = 0;
#pragma unroll 4
    for (int j = 0; j < 128; j++) {
        int p = j * 64 + l;
        float4 v = P[p];
        float dot = __fadd_rn(__fadd_rn(__fmul_rn(q.x, v.x), __fmul_rn(q.y, v.y)),
                              __fmul_rn(q.z, v.z));
        float d = __fadd_rn(__fsub_rn(q.w, __fmul_rn(2.0f, dot)), v.w);
        unsigned u = sortable(d);
        dk[SKEW(p)] = u;
        if (u < bmin) { bmin = u; bpos = p; }   // ascending p -> earliest index on tie
    }
    __syncthreads();

    unsigned resv = 0;
    int resp = 0, pos0 = 0;
    for (int k = 0; k < GG; k++) {
        // wave min of per-lane bmin (value only), then resolve the position
        unsigned mv = bmin;
        mv = dpp_minu<0x111, 0xF>(mv);
        mv = dpp_minu<0x112, 0xF>(mv);
        mv = dpp_minu<0x114, 0xF>(mv);
        mv = dpp_minu<0x118, 0xF>(mv);
        mv = dpp_minu<0x142, 0xA>(mv);
        mv = dpp_minu<0x143, 0xC>(mv);
        unsigned wmin = (unsigned)__builtin_amdgcn_readlane((int)mv, 63);
        unsigned long long mask = __ballot(bmin == wmin);
        int wpos;
        if (__builtin_popcountll(mask) == 1) {
            int owner = __builtin_ctzll(mask);
            wpos = __builtin_amdgcn_readlane(bpos, owner);
        } else {
            // exact tie fallback: u64 (value, pos) butterfly min
            unsigned long long kk =
                ((unsigned long long)bmin << 32) | (unsigned)bpos;
#pragma unroll
            for (int m = 1; m < 64; m <<= 1) {
                unsigned long long o = __shfl_xor(kk, m, 64);
                kk = (o < kk) ? o : kk;
            }
            wpos = (int)(kk & 0xFFFFFFFFull);
        }
        if (k == 0) pos0 = wpos;
        if (l == k) { resv = wmin; resp = wpos; }
        int own = wpos & 63;
        if (l == own) dk[SKEW(wpos)] = 0xFFFFFFFFu;   // invalidate popped slot
        __syncthreads();
        // cooperative rescan of owner's column (its 128 points)
        int p1 = l * 64 + own;
        int p2 = (l + 64) * 64 + own;
        unsigned v1 = dk[SKEW(p1)], v2 = dk[SKEW(p2)];
        bool c = v2 < v1;                 // p1 < p2, so tie keeps earliest
        unsigned cv = c ? v2 : v1;
        int cp = c ? p2 : p1;
        unsigned cm = cv;
        cm = dpp_minu<0x111, 0xF>(cm);
        cm = dpp_minu<0x112, 0xF>(cm);
        cm = dpp_minu<0x114, 0xF>(cm);
        cm = dpp_minu<0x118, 0xF>(cm);
        cm = dpp_minu<0x142, 0xA>(cm);
        cm = dpp_minu<0x143, 0xC>(cm);
        unsigned colmin = (unsigned)__builtin_amdgcn_readlane((int)cm, 63);
        unsigned long long m2 = __ballot(cv == colmin);
        int colpos;
        if (__builtin_popcountll(m2) == 1) {
            colpos = __builtin_amdgcn_readlane(cp, __builtin_ctzll(m2));
        } else {
            unsigned long long kk =
                ((unsigned long long)cv << 32) | (unsigned)cp;
#pragma unroll
            for (int m = 1; m < 64; m <<= 1) {
                unsigned long long o = __shfl_xor(kk, m, 64);
                kk = (o < kk) ? o : kk;
            }
            colpos = (int)(kk & 0xFFFFFFFFull);
        }
        if (l == own) { bmin = colmin; bpos = colpos; }
        __syncthreads();
    }
    if (l < GG) {
        gidx[(long)Q * GG + l] = (resv > SORT_R2) ? pos0 : resp;
    }
}

// ---------------------------------------------------------------------------
// Kernel 5: gather + 1x1 conv (W: 128x67) + relu + max over group.
// Block = 256 thr = 4 waves = 4 queries; W rows live in registers.
// ---------------------------------------------------------------------------
__global__ __launch_bounds__(256, 2) void k_mlp(const float4* __restrict__ pts4,
                                                const float* __restrict__ feaT,
                                                const float4* __restrict__ qpts,
                                                const int* __restrict__ gidx,
                                                const float* __restrict__ W,
                                                float* __restrict__ out) {
    __shared__ float sm[8704];   // max(8576 W floats, 4*32*68 grouped floats)
    int t = threadIdx.x, l = t & 63, w = t >> 6;

    for (int i = t; i < 8576; i += 256) sm[i] = W[i];
    __syncthreads();
    float wa[68], wb[68];
#pragma unroll
    for (int c = 0; c < 68; c++) {
        wa[c] = (c < 67) ? sm[l * 67 + c] : 0.f;
        wb[c] = (c < 67) ? sm[(l + 64) * 67 + c] : 0.f;
    }
    __syncthreads();   // done reading W region before reuse

    int Q = blockIdx.x * 4 + w;
    int b = Q >> 10, s = Q & 1023;
    float4 q = qpts[Q];
    const int* gi = gidx + (long)Q * GG;
    int base = w * 2176;   // 32*68 per wave

    if (l < 32) {
        int idx = gi[l];
        float4 p = pts4[(long)b * NN + idx];
        float4 rc = make_float4(__fsub_rn(p.x, q.x), __fsub_rn(p.y, q.y),
                                __fsub_rn(p.z, q.z), 0.f);
        *(float4*)&sm[base + l * 68 + 64] = rc;
    }
    {
        int g = l >> 1, half = l & 1;
        int idx = gi[g];
        const float4* f4 = (const float4*)(feaT + ((long)b * NN + idx) * 64);
#pragma unroll
        for (int k = 0; k < 8; k++) {
            *(float4*)&sm[base + g * 68 + half * 32 + k * 4] = f4[half * 8 + k];
        }
    }
    __syncthreads();

    float m0 = -1e30f, m1 = -1e30f;
#pragma unroll 2
    for (int g = 0; g < GG; g++) {
        float a0 = 0.f, a1 = 0.f;
#pragma unroll
        for (int c4 = 0; c4 < 17; c4++) {
            float4 gv = *(float4*)&sm[base + g * 68 + c4 * 4];
            a0 = fmaf(gv.x, wa[4 * c4 + 0], a0);
            a0 = fmaf(gv.y, wa[4 * c4 + 1], a0);
            a0 = fmaf(gv.z, wa[4 * c4 + 2], a0);
            a0 = fmaf(gv.w, wa[4 * c4 + 3], a0);
            a1 = fmaf(gv.x, wb[4 * c4 + 0], a1);
            a1 = fmaf(gv.y, wb[4 * c4 + 1], a1);
            a1 = fmaf(gv.z, wb[4 * c4 + 2], a1);
            a1 = fmaf(gv.w, wb[4 * c4 + 3], a1);
        }
        m0 = fmaxf(m0, a0);
        m1 = fmaxf(m1, a1);
    }
    // outputs: (B,3,S) then (B,128,S); relu(max) == max(relu)
    out[49152 + ((long)b * 128 + l) * SS + s]      = fmaxf(m0, 0.f);
    out[49152 + ((long)b * 128 + l + 64) * SS + s] = fmaxf(m1, 0.f);
}

// ---------------------------------------------------------------------------
extern "C" void kernel_launch(void* const* d_in, const int* in_sizes, int n_in,
                              void* d_out, int out_size, void* d_ws, size_t ws_size,
                              hipStream_t stream) {
    const float* coor = (const float*)d_in[0];   // (16,3,8192)
    const float* fea  = (const float*)d_in[1];   // (16,64,8192)
    const float* Wm   = (const float*)d_in[2];   // (128,67)
    float* out = (float*)d_out;

    char* ws = (char*)d_ws;
    float4* pts4 = (float4*)ws;                               //  2 MB
    float*  feaT = (float*)(ws + 2097152);                    // 32 MB
    float4* qpts = (float4*)(ws + 2097152 + 33554432);        // 256 KB
    int*    gidx = (int*)(ws + 2097152 + 33554432 + 262144);  //  2 MB

    k_pts<<<(BB * NN) / 256, 256, 0, stream>>>(coor, pts4);
    k_tr<<<dim3(NN / 64, BB), 256, 0, stream>>>(fea, feaT);
    k_fps<<<BB, 512, 0, stream>>>(pts4, qpts, out);
    k_knn<<<BB * SS, 64, 0, stream>>>(pts4, qpts, gidx);
    k_mlp<<<(BB * SS) / 4, 256, 0, stream>>>(pts4, feaT, qpts, gidx, Wm, out);
}